// Round 20
// baseline (393.415 us; speedup 1.0000x reference)
//
#include <hip/hip_runtime.h>
#include <stddef.h>

#define EPS 1e-5f
#define N_HW 3136              // 56*56
#define G 32                   // full batch, single pass
#define NG (G * N_HW)          // 100352 = GEMM N dimension
#define DIMC 800
#define NTILE 49               // 3136/64: 64-col tiles per image

typedef unsigned short u16;
typedef __attribute__((ext_vector_type(8))) short short8;
typedef __attribute__((ext_vector_type(4))) float floatx4;

__device__ __forceinline__ u16 f2b(float f) {
  unsigned u = __float_as_uint(f);
  u += 0x7FFFu + ((u >> 16) & 1u);        // round-to-nearest-even
  return (u16)(u >> 16);
}
__device__ __forceinline__ float blo(unsigned u) { return __uint_as_float(u << 16); }
__device__ __forceinline__ float bhi(unsigned u) { return __uint_as_float(u & 0xFFFF0000u); }

// ---------------- ws layout (bytes) ----------------
static const size_t XA_OFF  = 0;
static const size_t H0_OFF  = 122028032ull;
static const size_t BLK_OFF = 134873088ull;
static const size_t GWB_OFF = 173408256ull;
static const size_t STS_OFF = 174688256ull;
static const size_t STQ_OFF = 174712832ull;
static const size_t PAT_OFF = 174737408ull;
static const size_t M4_OFF  = 179456000ull;
static const size_t MH_OFF  = M4_OFF + 6144 * 4;
static const size_t OP_OFF  = MH_OFF + 6144 * 4;
static const size_t NEED    = OP_OFF + 6144 * 4;   // ~179.5 MB

// ---------------- small utility kernels ----------------
__global__ __launch_bounds__(256) void gw2bf(const float* __restrict__ gw, u16* __restrict__ gwb) {
  int i = (blockIdx.x * 256 + threadIdx.x) * 4;   // 640000 elems, 625 blocks
  float4 v = *(const float4*)(gw + i);
  gwb[i + 0] = f2b(v.x); gwb[i + 1] = f2b(v.y);
  gwb[i + 2] = f2b(v.z); gwb[i + 3] = f2b(v.w);
}

__global__ __launch_bounds__(256) void zero_stats(float* __restrict__ p) {
  p[blockIdx.x * 256 + threadIdx.x] = 0.f;        // 12288 floats, 48 blocks
}

// ---------------- stem conv1: LDS-tiled, all 16 ch per block ----------------
#define XT_PITCH 226
#define XT_CH (17 * XT_PITCH)          // 3842
__global__ __launch_bounds__(256) void stem_conv1(
    const float* __restrict__ xg, const float* __restrict__ w, const float* __restrict__ b1,
    const float* __restrict__ g, const float* __restrict__ bb,
    const float* __restrict__ m, const float* __restrict__ v,
    float* __restrict__ h1) {
  __shared__ float xt[3 * XT_CH];      // 46.1 KB
  __shared__ float wt[16 * 27];
  __shared__ float mulc[16], addc[16];
  int blk = blockIdx.x;                // s + 14*bg
  int s = blk % 14;
  int bg = blk / 14;
  int tid = threadIdx.x;

  for (int e = tid; e < 432; e += 256) wt[e] = w[e];
  if (tid < 16) {
    float A = g[tid] * rsqrtf(v[tid] + EPS);
    mulc[tid] = A;
    addc[tid] = (b1[tid] - m[tid]) * A + bb[tid];
  }
  int iy0 = 16 * s - 1;
  for (int e = tid; e < 3 * XT_CH; e += 256) {
    int ci = e / XT_CH;
    int rem = e - ci * XT_CH;
    int r = rem / XT_PITCH;
    int cc = rem - r * XT_PITCH;
    int iy = iy0 + r, ix = cc - 1;
    float val = 0.f;
    if (iy >= 0 && iy < 224 && ix >= 0 && ix < 224)
      val = xg[((size_t)(bg * 3 + ci)) * 224 * 224 + iy * 224 + ix];
    xt[e] = val;
  }
  __syncthreads();

  for (int p = tid; p < 8 * 112; p += 256) {
    int oyl = p / 112, ox = p - oyl * 112;
    float xv[27];
#pragma unroll
    for (int ci = 0; ci < 3; ci++)
#pragma unroll
      for (int ky = 0; ky < 3; ky++)
#pragma unroll
        for (int kx = 0; kx < 3; kx++)
          xv[ci * 9 + ky * 3 + kx] = xt[ci * XT_CH + (2 * oyl + ky) * XT_PITCH + 2 * ox + kx];
    int oy = 8 * s + oyl;
#pragma unroll
    for (int c = 0; c < 16; c++) {
      float acc = 0.f;
#pragma unroll
      for (int t = 0; t < 27; t++) acc += xv[t] * wt[c * 27 + t];
      float y = acc * mulc[c] + addc[c];
      h1[(size_t)(c * G + bg) * 12544 + oy * 112 + ox] = fmaxf(y, 0.f);
    }
  }
}

__global__ __launch_bounds__(256) void stem_dw(
    const float* __restrict__ h1, const float* __restrict__ dw, const float* __restrict__ dwb,
    float* __restrict__ h2) {
  int idx = blockIdx.x * 256 + threadIdx.x;       // ((c*G)+bg)*3136 + q
  int q = idx % N_HW;
  int t = idx / N_HW;
  int bg = t & (G - 1);
  int c = t >> 5;
  int qy = q / 56, qx = q % 56;
  const float* plane = h1 + (size_t)(c * G + bg) * 12544;
  float acc = dwb[c];
#pragma unroll
  for (int ky = 0; ky < 3; ky++) {
    int iy = qy * 2 - 1 + ky;
    if (iy < 0 || iy >= 112) continue;
#pragma unroll
    for (int kx = 0; kx < 3; kx++) {
      int ix = qx * 2 - 1 + kx;
      if (ix < 0 || ix >= 112) continue;
      acc += plane[iy * 112 + ix] * dw[c * 9 + ky * 3 + kx];
    }
  }
  h2[idx] = acc;
}

__global__ __launch_bounds__(256) void stem_pw(
    const float* __restrict__ h2, const float* __restrict__ w2, const float* __restrict__ b2,
    const float* __restrict__ g, const float* __restrict__ bb,
    const float* __restrict__ m, const float* __restrict__ v,
    float* __restrict__ H0) {
  int idx = blockIdx.x * 256 + threadIdx.x;       // ((o*G)+bg)*3136 + q
  int q = idx % N_HW;
  int t = idx / N_HW;
  int bg = t & (G - 1);
  int o = t >> 5;
  float acc = b2[o];
#pragma unroll
  for (int c = 0; c < 16; c++) acc += w2[o * 16 + c] * h2[(size_t)(c * G + bg) * N_HW + q];
  float y = (acc - m[o]) * (g[o] * rsqrtf(v[o] + EPS)) + bb[o];
  H0[idx] = y;
}

// ------- fused instance-norm stats + norm + relu + depthwise 3x3 (pad 1) -------
template <typename T>
__global__ __launch_bounds__(256) void dw_fused(
    const T* __restrict__ base, const float* __restrict__ cdw,
    const float* __restrict__ in_g, const float* __restrict__ in_b,
    u16* __restrict__ XA, int cdwoff) {
  __shared__ float sm[58 * 58];
  __shared__ float wred[8];
  int blk = blockIdx.x;            // cl*G + bg
  int cl = blk >> 5;
  int c = cdwoff + cl;
  int tid = threadIdx.x;

  // halo-only zero init (rows 0,57; cols 0,57 of rows 1..56)
  if (tid < 58) { sm[tid] = 0.f; sm[57 * 58 + tid] = 0.f; }
  if (tid >= 64 && tid < 120) { int r = tid - 63; sm[r * 58] = 0.f; sm[r * 58 + 57] = 0.f; }

  const T* row = base + (size_t)blk * N_HW;
  float s = 0.f, s2 = 0.f;
  for (int i = tid; i < 392; i += 256) {
    float vals[8];
    if constexpr (sizeof(T) == 2) {
      uint4 u = *(const uint4*)((const u16*)row + i * 8);
      vals[0] = blo(u.x); vals[1] = bhi(u.x);
      vals[2] = blo(u.y); vals[3] = bhi(u.y);
      vals[4] = blo(u.z); vals[5] = bhi(u.z);
      vals[6] = blo(u.w); vals[7] = bhi(u.w);
    } else {
      float4 v0 = *(const float4*)((const float*)row + i * 8);
      float4 v1 = *(const float4*)((const float*)row + i * 8 + 4);
      vals[0] = v0.x; vals[1] = v0.y; vals[2] = v0.z; vals[3] = v0.w;
      vals[4] = v1.x; vals[5] = v1.y; vals[6] = v1.z; vals[7] = v1.w;
    }
    int p = i * 8;
    int y = p / 56, x = p - y * 56;
    float* d = &sm[(y + 1) * 58 + x + 1];
#pragma unroll
    for (int e = 0; e < 8; e++) {
      d[e] = vals[e];
      s += vals[e];
      s2 += vals[e] * vals[e];
    }
  }
#pragma unroll
  for (int o = 32; o > 0; o >>= 1) {
    s += __shfl_down(s, o);
    s2 += __shfl_down(s2, o);
  }
  if ((tid & 63) == 0) { wred[(tid >> 6) * 2] = s; wred[(tid >> 6) * 2 + 1] = s2; }
  __syncthreads();
  float ts = (wred[0] + wred[2]) + (wred[4] + wred[6]);
  float tq = (wred[1] + wred[3]) + (wred[5] + wred[7]);
  float mean = ts * (1.f / N_HW);
  float var = fmaxf(tq * (1.f / N_HW) - mean * mean, 0.f);
  float sc = in_g[c] * rsqrtf(var + EPS);
  float sh = in_b[c] - mean * sc;

  for (int i = tid; i < N_HW; i += 256) {
    int y = i / 56, x = i - y * 56;
    int pos = (y + 1) * 58 + x + 1;
    sm[pos] = fmaxf(sm[pos] * sc + sh, 0.f);
  }
  __syncthreads();

  float w0 = cdw[c * 9 + 0], w1 = cdw[c * 9 + 1], w2 = cdw[c * 9 + 2];
  float w3 = cdw[c * 9 + 3], w4 = cdw[c * 9 + 4], w5 = cdw[c * 9 + 5];
  float w6 = cdw[c * 9 + 6], w7 = cdw[c * 9 + 7], w8 = cdw[c * 9 + 8];
  u16* outp = XA + (size_t)blk * N_HW;
  for (int pp = tid; pp < N_HW / 2; pp += 256) {   // pairs (56 even -> same row)
    int p = pp * 2;
    int y = p / 56, x = p - y * 56;
    const float* p0 = &sm[y * 58 + x];
    float a0 = p0[0] * w0 + p0[1] * w1 + p0[2] * w2
             + p0[58] * w3 + p0[59] * w4 + p0[60] * w5
             + p0[116] * w6 + p0[117] * w7 + p0[118] * w8;
    float a1 = p0[1] * w0 + p0[2] * w1 + p0[3] * w2
             + p0[59] * w3 + p0[60] * w4 + p0[61] * w5
             + p0[117] * w6 + p0[118] * w7 + p0[119] * w8;
    unsigned pk = (unsigned)f2b(a0) | ((unsigned)f2b(a1) << 16);
    *(unsigned*)&outp[p] = pk;
  }
}

// ---------------- MFMA GEMM: C[192][NG] = A[192][K] @ B[K][NG] ----------------
// M-SPLIT variant: M-tile 96 (acc 24 AGPR, ~5-6 waves/SIMD residency), grid
// NG/32 = 3136 (~12 blocks/CU). Adjacent swizzled blocks = the two M-halves of
// one column tile -> B panel shared in the same XCD's L2. Double-buffered LDS,
// depth-2 B prefetch, 1 barrier/iter, XCD-bijective swizzle.
// MODE 0: store bf16 C.  MODE 1 (L3): per-row stats atomics + f32 patch spill.
template <int MODE>
__global__ __launch_bounds__(256) void gemm_mfma(
    const u16* __restrict__ A, const u16* __restrict__ B, u16* __restrict__ C,
    float* __restrict__ statS, float* __restrict__ statQ, float* __restrict__ patchf,
    int K) {
  __shared__ u16 As[2][96][40];    // pitch 80 B, 15.36 KB total
  __shared__ u16 Bs[2][32][64];    // pitch 128 B, XOR-16 column swizzle, 8 KB
  // T1: bijective XCD swizzle (gridDim.x % 8 == 0)
  int nwg = gridDim.x;
  int cpx = nwg >> 3;
  int j = (blockIdx.x & 7) * cpx + (blockIdx.x >> 3);
  int jm = j & 1;                           // M half (0: rows 0-95, 1: 96-191)
  int jc = j >> 1;                          // column tile 0..1567
  int n0 = jc * 64;
  int m0 = jm * 96;
  int tid = threadIdx.x;
  int wave = tid >> 6, lane = tid & 63;
  int wm = wave >> 1, wn = wave & 1;        // wave tile 48m x 32n
  int lg = lane >> 4, li = lane & 15;
  floatx4 acc[3][2] = {};

  int ar = tid >> 2, ak = (tid & 3) * 8;    // rows 0-63; rows 64-95 via ar<32
  int bk = tid >> 3, bn = (tid & 7) * 8;
  int bnx = bn ^ ((bk >> 3) << 4);
  const u16* Ag = A + (size_t)(m0 + ar) * DIMC + ak;
  const u16* Bg = B + (size_t)bk * NG + n0 + bn;

  int nt = K / 32;
  // prologue: A(0) depth-1; B depth-2 (B(0) to write now, B(1) in flight)
  uint4 ra0 = *(const uint4*)(Ag);
  uint4 ra1 = {0, 0, 0, 0};
  if (ar < 32) ra1 = *(const uint4*)(Ag + (size_t)64 * DIMC);
  uint4 rb_w = *(const uint4*)(Bg);
  uint4 rb_f = (nt > 1) ? *(const uint4*)(Bg + (size_t)32 * NG) : rb_w;

  for (int t = 0; t < nt; t++) {
    int cur = t & 1;
    *(uint4*)&As[cur][ar][ak] = ra0;
    if (ar < 32) *(uint4*)&As[cur][ar + 64][ak] = ra1;
    *(uint4*)&Bs[cur][bk][bnx] = rb_w;
    uint4 rb_new;
    bool pfA = (t + 1 < nt);
    bool pfB = (t + 2 < nt);
    if (pfA) {                                  // A(t+1): 1 phase slack (L2)
      const u16* ag = Ag + (size_t)(t + 1) * 32;
      ra0 = *(const uint4*)(ag);
      if (ar < 32) ra1 = *(const uint4*)(ag + (size_t)64 * DIMC);
    }
    if (pfB)                                    // B(t+2): 2 phases slack (L3)
      rb_new = *(const uint4*)(Bg + (size_t)(t + 2) * 32 * NG);
    __syncthreads();
    short8 aF[3];
#pragma unroll
    for (int mi = 0; mi < 3; mi++)
      aF[mi] = *(const short8*)&As[cur][wm * 48 + mi * 16 + li][lg * 8];
#pragma unroll
    for (int ni = 0; ni < 2; ni++) {
      int colx = ((wn * 32 + ni * 16) ^ (lg << 4)) + li;
      short8 bF;
#pragma unroll
      for (int e = 0; e < 8; e++) bF[e] = (short)Bs[cur][lg * 8 + e][colx];
#pragma unroll
      for (int mi = 0; mi < 3; mi++)
        acc[mi][ni] = __builtin_amdgcn_mfma_f32_16x16x32_bf16(aF[mi], bF, acc[mi][ni], 0, 0, 0);
    }
    __syncthreads();                            // all reads done before next write
    rb_w = rb_f;
    if (pfB) rb_f = rb_new;
  }

  if constexpr (MODE == 0) {
#pragma unroll
    for (int mi = 0; mi < 3; mi++) {
#pragma unroll
      for (int ni = 0; ni < 2; ni++) {
        int row = m0 + wm * 48 + mi * 16 + lg * 4;  // C/D: col=lane&15, row=lg*4+r
        int col = n0 + wn * 32 + ni * 16 + li;
        u16* cp = C + (size_t)row * NG + col;
#pragma unroll
        for (int r = 0; r < 4; r++) cp[(size_t)r * NG] = f2b(acc[mi][ni][r]);
      }
    }
  } else {
    int bg = jc / NTILE;
    int tile = jc % NTILE;
#pragma unroll
    for (int mi = 0; mi < 3; mi++) {
#pragma unroll
      for (int r = 0; r < 4; r++) {
        float v0 = acc[mi][0][r], v1 = acc[mi][1][r];
        float s = v0 + v1;
        float q = v0 * v0 + v1 * v1;
#pragma unroll
        for (int msk = 1; msk < 16; msk <<= 1) {
          s += __shfl_xor(s, msk);
          q += __shfl_xor(q, msk);
        }
        if (li == 0) {
          int row = m0 + wm * 48 + mi * 16 + lg * 4 + r;
          atomicAdd(&statS[row * 32 + bg], s);
          atomicAdd(&statQ[row * 32 + bg], q);
        }
      }
    }
    if (tile >= 22 && tile <= 24) {
#pragma unroll
      for (int mi = 0; mi < 3; mi++) {
#pragma unroll
        for (int ni = 0; ni < 2; ni++) {
          int row = m0 + wm * 48 + mi * 16 + lg * 4;
          int pc = (tile - 22) * 64 + wn * 32 + ni * 16 + li;
#pragma unroll
          for (int r = 0; r < 4; r++)
            patchf[((size_t)(row + r) * 32 + bg) * 192 + pc] = acc[mi][ni][r];
        }
      }
    }
  }
}

// ------- head: layer-4 norm + dwconv on patch, stats from GEMM epilogue -------
__global__ __launch_bounds__(256) void head_m4(
    const float* __restrict__ statS, const float* __restrict__ statQ,
    const float* __restrict__ patchf,
    const float* __restrict__ in_g, const float* __restrict__ in_b,
    const float* __restrict__ cdw, float* __restrict__ m4, float* __restrict__ meanH) {
  int idx = blockIdx.x * 256 + threadIdx.x;   // cl*32 + bg
  if (idx >= 192 * 32) return;
  int cl = idx >> 5;
  int c = 608 + cl;
  float mean = statS[idx] * (1.f / N_HW);
  float var = fmaxf(statQ[idx] * (1.f / N_HW) - mean * mean, 0.f);
  float sc = in_g[c] * rsqrtf(var + EPS);
  float sh = in_b[c] - mean * sc;
  const float* pf = patchf + (size_t)idx * 192;
  float val[4][4];
#pragma unroll
  for (int dy = 0; dy < 4; dy++)
#pragma unroll
    for (int dx = 0; dx < 4; dx++) {
      int hw = (25 + dy) * 56 + 25 + dx;
      float v = pf[((hw >> 6) - 22) * 64 + (hw & 63)];
      val[dy][dx] = fmaxf(v * sc + sh, 0.f);
    }
  const float* w = cdw + c * 9;
  float acc = 0.f;
#pragma unroll
  for (int oy = 1; oy < 3; oy++)
#pragma unroll
    for (int ox = 1; ox < 3; ox++)
#pragma unroll
      for (int ky = 0; ky < 3; ky++)
#pragma unroll
        for (int kx = 0; kx < 3; kx++)
          acc += val[oy + ky - 1][ox + kx - 1] * w[ky * 3 + kx];
  m4[idx] = acc * 0.25f;
  float mh = 0.f;
#pragma unroll
  for (int dy = 0; dy < 2; dy++)
#pragma unroll
    for (int dx = 0; dx < 2; dx++) {
      int hw = (26 + dy) * 56 + 26 + dx;
      mh += pf[((hw >> 6) - 22) * 64 + (hw & 63)];
    }
  meanH[idx] = mh * 0.25f;
}

__global__ __launch_bounds__(256) void head_mix(
    const float* __restrict__ gw, const float* __restrict__ m4, const float* __restrict__ meanH,
    float* __restrict__ out_pre) {
  int idx = blockIdx.x * 256 + threadIdx.x;   // bg*192 + j
  if (idx >= G * 192) return;
  int j = idx % 192;
  int bg = idx / 192;
  float acc = meanH[j * G + bg];
  const float* grow = gw + (size_t)(608 + j) * DIMC + 608;
  for (int c = 0; c < 192; c++) acc += grow[c] * m4[c * G + bg];
  out_pre[idx] = acc;
}

__global__ __launch_bounds__(256) void head_fc(
    const float* __restrict__ out_pre, const float* __restrict__ fc_w,
    const float* __restrict__ fc_b, float* __restrict__ outg) {
  int idx = blockIdx.x * 256 + threadIdx.x;   // bg*1000 + t
  if (idx >= G * 1000) return;
  int t = idx % 1000;
  int bg = idx / 1000;
  float acc = fc_b[t];
  const float* wr = fc_w + (size_t)t * 192;
  const float* hr = out_pre + (size_t)bg * 192;
  for (int j = 0; j < 192; j++) acc += wr[j] * hr[j];
  outg[idx] = acc;
}

extern "C" void kernel_launch(void* const* d_in, const int* in_sizes, int n_in,
                              void* d_out, int out_size, void* d_ws, size_t ws_size,
                              hipStream_t stream) {
  const float* x      = (const float*)d_in[0];
  const float* ds_w1  = (const float*)d_in[1];
  const float* ds_b1  = (const float*)d_in[2];
  const float* bn1_g  = (const float*)d_in[3];
  const float* bn1_b  = (const float*)d_in[4];
  const float* bn1_m  = (const float*)d_in[5];
  const float* bn1_v  = (const float*)d_in[6];
  const float* ds_dw  = (const float*)d_in[7];
  const float* ds_dwb = (const float*)d_in[8];
  const float* ds_w2  = (const float*)d_in[9];
  const float* ds_b2  = (const float*)d_in[10];
  const float* bn2_g  = (const float*)d_in[11];
  const float* bn2_b  = (const float*)d_in[12];
  const float* bn2_m  = (const float*)d_in[13];
  const float* bn2_v  = (const float*)d_in[14];
  const float* cdw    = (const float*)d_in[15];
  const float* gw     = (const float*)d_in[16];
  const float* in_g   = (const float*)d_in[17];
  const float* in_b   = (const float*)d_in[18];
  const float* fc_w   = (const float*)d_in[19];
  const float* fc_b   = (const float*)d_in[20];
  float* out = (float*)d_out;
  char* ws = (char*)d_ws;

  if (ws_size < NEED) return;

  u16*   XAc    = (u16*)(ws + XA_OFF);
  float* H0     = (float*)(ws + H0_OFF);
  u16*   blockb = (u16*)(ws + BLK_OFF);
  u16*   gwb    = (u16*)(ws + GWB_OFF);
  float* statS  = (float*)(ws + STS_OFF);
  float* statQ  = (float*)(ws + STQ_OFF);
  float* patchf = (float*)(ws + PAT_OFF);
  float* m4     = (float*)(ws + M4_OFF);
  float* meanH  = (float*)(ws + MH_OFF);
  float* opre   = (float*)(ws + OP_OFF);
  float* h1     = (float*)(ws + BLK_OFF);           // stem temps alias blockb
  float* h2     = h1 + (size_t)16 * G * 12544;

  gw2bf<<<625, 256, 0, stream>>>(gw, gwb);
  zero_stats<<<48, 256, 0, stream>>>(statS);        // statS+statQ contiguous

  static const int CDWOFF[4] = {0, 32, 224, 416};   // dw layer channel base
  static const int SZ[4]     = {32, 192, 192, 192};
  static const int RA[4]     = {32, 224, 416, 608}; // gemm output channel base
  static const int KK[4]     = {32, 224, 416, 608};

  stem_conv1<<<14 * G, 256, 0, stream>>>(
      x, ds_w1, ds_b1, bn1_g, bn1_b, bn1_m, bn1_v, h1);
  stem_dw<<<16 * G * N_HW / 256, 256, 0, stream>>>(h1, ds_dw, ds_dwb, h2);
  stem_pw<<<32 * G * N_HW / 256, 256, 0, stream>>>(
      h2, ds_w2, ds_b2, bn2_g, bn2_b, bn2_m, bn2_v, H0);

  for (int i = 0; i < 4; i++) {
    if (i == 0)
      dw_fused<float><<<SZ[i] * G, 256, 0, stream>>>(
          H0, cdw, in_g, in_b, XAc + (size_t)CDWOFF[i] * NG, CDWOFF[i]);
    else
      dw_fused<u16><<<SZ[i] * G, 256, 0, stream>>>(
          blockb, cdw, in_g, in_b, XAc + (size_t)CDWOFF[i] * NG, CDWOFF[i]);
    if (i < 3)
      gemm_mfma<0><<<NG / 32, 256, 0, stream>>>(
          gwb + (size_t)RA[i] * DIMC, XAc, blockb, nullptr, nullptr, nullptr, KK[i]);
    else
      gemm_mfma<1><<<NG / 32, 256, 0, stream>>>(
          gwb + (size_t)RA[i] * DIMC, XAc, nullptr, statS, statQ, patchf, KK[i]);
  }

  head_m4<<<24, 256, 0, stream>>>(statS, statQ, patchf, in_g, in_b, cdw, m4, meanH);
  head_mix<<<(G * 192 + 255) / 256, 256, 0, stream>>>(gw, m4, meanH, opre);
  head_fc<<<(G * 1000 + 255) / 256, 256, 0, stream>>>(opre, fc_w, fc_b, out);
}

// Round 21
// 372.257 us; speedup vs baseline: 1.0568x; 1.0568x over previous
//
#include <hip/hip_runtime.h>
#include <stddef.h>

#define EPS 1e-5f
#define N_HW 3136              // 56*56
#define G 32                   // full batch, single pass
#define NG (G * N_HW)          // 100352 = GEMM N dimension
#define DIMC 800
#define NTILE 49               // 3136/64: 64-col tiles per image

typedef unsigned short u16;
typedef __attribute__((ext_vector_type(8))) short short8;
typedef __attribute__((ext_vector_type(4))) float floatx4;

__device__ __forceinline__ u16 f2b(float f) {
  unsigned u = __float_as_uint(f);
  u += 0x7FFFu + ((u >> 16) & 1u);        // round-to-nearest-even
  return (u16)(u >> 16);
}
__device__ __forceinline__ float blo(unsigned u) { return __uint_as_float(u << 16); }
__device__ __forceinline__ float bhi(unsigned u) { return __uint_as_float(u & 0xFFFF0000u); }

// ---------------- ws layout (bytes) ----------------
static const size_t XA_OFF  = 0;
static const size_t H0_OFF  = 122028032ull;
static const size_t BLK_OFF = 134873088ull;
static const size_t GWB_OFF = 173408256ull;
static const size_t STS_OFF = 174688256ull;
static const size_t STQ_OFF = 174712832ull;
static const size_t PAT_OFF = 174737408ull;
static const size_t M4_OFF  = 179456000ull;
static const size_t MH_OFF  = M4_OFF + 6144 * 4;
static const size_t OP_OFF  = MH_OFF + 6144 * 4;
static const size_t NEED    = OP_OFF + 6144 * 4;   // ~179.5 MB

// ---------------- small utility kernels ----------------
__global__ __launch_bounds__(256) void gw2bf(const float* __restrict__ gw, u16* __restrict__ gwb) {
  int i = (blockIdx.x * 256 + threadIdx.x) * 4;   // 640000 elems, 625 blocks
  float4 v = *(const float4*)(gw + i);
  gwb[i + 0] = f2b(v.x); gwb[i + 1] = f2b(v.y);
  gwb[i + 2] = f2b(v.z); gwb[i + 3] = f2b(v.w);
}

__global__ __launch_bounds__(256) void zero_stats(float* __restrict__ p) {
  p[blockIdx.x * 256 + threadIdx.x] = 0.f;        // 12288 floats, 48 blocks
}

// ---------------- stem conv1: LDS-tiled, all 16 ch per block ----------------
#define XT_PITCH 226
#define XT_CH (17 * XT_PITCH)          // 3842
__global__ __launch_bounds__(256) void stem_conv1(
    const float* __restrict__ xg, const float* __restrict__ w, const float* __restrict__ b1,
    const float* __restrict__ g, const float* __restrict__ bb,
    const float* __restrict__ m, const float* __restrict__ v,
    float* __restrict__ h1) {
  __shared__ float xt[3 * XT_CH];      // 46.1 KB
  __shared__ float wt[16 * 27];
  __shared__ float mulc[16], addc[16];
  int blk = blockIdx.x;                // s + 14*bg
  int s = blk % 14;
  int bg = blk / 14;
  int tid = threadIdx.x;

  for (int e = tid; e < 432; e += 256) wt[e] = w[e];
  if (tid < 16) {
    float A = g[tid] * rsqrtf(v[tid] + EPS);
    mulc[tid] = A;
    addc[tid] = (b1[tid] - m[tid]) * A + bb[tid];
  }
  int iy0 = 16 * s - 1;
  for (int e = tid; e < 3 * XT_CH; e += 256) {
    int ci = e / XT_CH;
    int rem = e - ci * XT_CH;
    int r = rem / XT_PITCH;
    int cc = rem - r * XT_PITCH;
    int iy = iy0 + r, ix = cc - 1;
    float val = 0.f;
    if (iy >= 0 && iy < 224 && ix >= 0 && ix < 224)
      val = xg[((size_t)(bg * 3 + ci)) * 224 * 224 + iy * 224 + ix];
    xt[e] = val;
  }
  __syncthreads();

  for (int p = tid; p < 8 * 112; p += 256) {
    int oyl = p / 112, ox = p - oyl * 112;
    float xv[27];
#pragma unroll
    for (int ci = 0; ci < 3; ci++)
#pragma unroll
      for (int ky = 0; ky < 3; ky++)
#pragma unroll
        for (int kx = 0; kx < 3; kx++)
          xv[ci * 9 + ky * 3 + kx] = xt[ci * XT_CH + (2 * oyl + ky) * XT_PITCH + 2 * ox + kx];
    int oy = 8 * s + oyl;
#pragma unroll
    for (int c = 0; c < 16; c++) {
      float acc = 0.f;
#pragma unroll
      for (int t = 0; t < 27; t++) acc += xv[t] * wt[c * 27 + t];
      float y = acc * mulc[c] + addc[c];
      h1[(size_t)(c * G + bg) * 12544 + oy * 112 + ox] = fmaxf(y, 0.f);
    }
  }
}

__global__ __launch_bounds__(256) void stem_dw(
    const float* __restrict__ h1, const float* __restrict__ dw, const float* __restrict__ dwb,
    float* __restrict__ h2) {
  int idx = blockIdx.x * 256 + threadIdx.x;       // ((c*G)+bg)*3136 + q
  int q = idx % N_HW;
  int t = idx / N_HW;
  int bg = t & (G - 1);
  int c = t >> 5;
  int qy = q / 56, qx = q % 56;
  const float* plane = h1 + (size_t)(c * G + bg) * 12544;
  float acc = dwb[c];
#pragma unroll
  for (int ky = 0; ky < 3; ky++) {
    int iy = qy * 2 - 1 + ky;
    if (iy < 0 || iy >= 112) continue;
#pragma unroll
    for (int kx = 0; kx < 3; kx++) {
      int ix = qx * 2 - 1 + kx;
      if (ix < 0 || ix >= 112) continue;
      acc += plane[iy * 112 + ix] * dw[c * 9 + ky * 3 + kx];
    }
  }
  h2[idx] = acc;
}

__global__ __launch_bounds__(256) void stem_pw(
    const float* __restrict__ h2, const float* __restrict__ w2, const float* __restrict__ b2,
    const float* __restrict__ g, const float* __restrict__ bb,
    const float* __restrict__ m, const float* __restrict__ v,
    float* __restrict__ H0) {
  int idx = blockIdx.x * 256 + threadIdx.x;       // ((o*G)+bg)*3136 + q
  int q = idx % N_HW;
  int t = idx / N_HW;
  int bg = t & (G - 1);
  int o = t >> 5;
  float acc = b2[o];
#pragma unroll
  for (int c = 0; c < 16; c++) acc += w2[o * 16 + c] * h2[(size_t)(c * G + bg) * N_HW + q];
  float y = (acc - m[o]) * (g[o] * rsqrtf(v[o] + EPS)) + bb[o];
  H0[idx] = y;
}

// ------- fused instance-norm stats + norm + relu + depthwise 3x3 (pad 1) -------
template <typename T>
__global__ __launch_bounds__(256) void dw_fused(
    const T* __restrict__ base, const float* __restrict__ cdw,
    const float* __restrict__ in_g, const float* __restrict__ in_b,
    u16* __restrict__ XA, int cdwoff) {
  __shared__ float sm[58 * 58];
  __shared__ float wred[8];
  int blk = blockIdx.x;            // cl*G + bg
  int cl = blk >> 5;
  int c = cdwoff + cl;
  int tid = threadIdx.x;

  // halo-only zero init (rows 0,57; cols 0,57 of rows 1..56)
  if (tid < 58) { sm[tid] = 0.f; sm[57 * 58 + tid] = 0.f; }
  if (tid >= 64 && tid < 120) { int r = tid - 63; sm[r * 58] = 0.f; sm[r * 58 + 57] = 0.f; }

  const T* row = base + (size_t)blk * N_HW;
  float s = 0.f, s2 = 0.f;
  for (int i = tid; i < 392; i += 256) {
    float vals[8];
    if constexpr (sizeof(T) == 2) {
      uint4 u = *(const uint4*)((const u16*)row + i * 8);
      vals[0] = blo(u.x); vals[1] = bhi(u.x);
      vals[2] = blo(u.y); vals[3] = bhi(u.y);
      vals[4] = blo(u.z); vals[5] = bhi(u.z);
      vals[6] = blo(u.w); vals[7] = bhi(u.w);
    } else {
      float4 v0 = *(const float4*)((const float*)row + i * 8);
      float4 v1 = *(const float4*)((const float*)row + i * 8 + 4);
      vals[0] = v0.x; vals[1] = v0.y; vals[2] = v0.z; vals[3] = v0.w;
      vals[4] = v1.x; vals[5] = v1.y; vals[6] = v1.z; vals[7] = v1.w;
    }
    int p = i * 8;
    int y = p / 56, x = p - y * 56;
    float* d = &sm[(y + 1) * 58 + x + 1];
#pragma unroll
    for (int e = 0; e < 8; e++) {
      d[e] = vals[e];
      s += vals[e];
      s2 += vals[e] * vals[e];
    }
  }
#pragma unroll
  for (int o = 32; o > 0; o >>= 1) {
    s += __shfl_down(s, o);
    s2 += __shfl_down(s2, o);
  }
  if ((tid & 63) == 0) { wred[(tid >> 6) * 2] = s; wred[(tid >> 6) * 2 + 1] = s2; }
  __syncthreads();
  float ts = (wred[0] + wred[2]) + (wred[4] + wred[6]);
  float tq = (wred[1] + wred[3]) + (wred[5] + wred[7]);
  float mean = ts * (1.f / N_HW);
  float var = fmaxf(tq * (1.f / N_HW) - mean * mean, 0.f);
  float sc = in_g[c] * rsqrtf(var + EPS);
  float sh = in_b[c] - mean * sc;

  for (int i = tid; i < N_HW; i += 256) {
    int y = i / 56, x = i - y * 56;
    int pos = (y + 1) * 58 + x + 1;
    sm[pos] = fmaxf(sm[pos] * sc + sh, 0.f);
  }
  __syncthreads();

  float w0 = cdw[c * 9 + 0], w1 = cdw[c * 9 + 1], w2 = cdw[c * 9 + 2];
  float w3 = cdw[c * 9 + 3], w4 = cdw[c * 9 + 4], w5 = cdw[c * 9 + 5];
  float w6 = cdw[c * 9 + 6], w7 = cdw[c * 9 + 7], w8 = cdw[c * 9 + 8];
  u16* outp = XA + (size_t)blk * N_HW;
  for (int pp = tid; pp < N_HW / 2; pp += 256) {   // pairs (56 even -> same row)
    int p = pp * 2;
    int y = p / 56, x = p - y * 56;
    const float* p0 = &sm[y * 58 + x];
    float a0 = p0[0] * w0 + p0[1] * w1 + p0[2] * w2
             + p0[58] * w3 + p0[59] * w4 + p0[60] * w5
             + p0[116] * w6 + p0[117] * w7 + p0[118] * w8;
    float a1 = p0[1] * w0 + p0[2] * w1 + p0[3] * w2
             + p0[59] * w3 + p0[60] * w4 + p0[61] * w5
             + p0[117] * w6 + p0[118] * w7 + p0[119] * w8;
    unsigned pk = (unsigned)f2b(a0) | ((unsigned)f2b(a1) << 16);
    *(unsigned*)&outp[p] = pk;
  }
}

// ---------------- MFMA GEMM: C[192][NG] = A[192][K] @ B[K][NG] ----------------
// BK=64 PAIR variant: r20 layouts (M-tile 96, dbuf LDS) but TWO 32-K tiles per
// barrier pair -> drain events per K=608 dispatch: 38 -> 20 (the one invariant
// all 10 prior ~110us variants shared). Single-tile prologue handles K%64==32.
// MODE 0: store bf16 C.  MODE 1 (L3): per-row stats atomics + f32 patch spill.
#define GEMM_COMPUTE(BUF)                                                       \
  {                                                                             \
    short8 aF[3];                                                               \
    _Pragma("unroll")                                                           \
    for (int mi = 0; mi < 3; mi++)                                              \
      aF[mi] = *(const short8*)&As[BUF][wm * 48 + mi * 16 + li][lg * 8];        \
    _Pragma("unroll")                                                           \
    for (int ni = 0; ni < 2; ni++) {                                            \
      int colx = ((wn * 32 + ni * 16) ^ (lg << 4)) + li;                        \
      short8 bF;                                                                \
      _Pragma("unroll")                                                         \
      for (int e = 0; e < 8; e++) bF[e] = (short)Bs[BUF][lg * 8 + e][colx];     \
      _Pragma("unroll")                                                         \
      for (int mi = 0; mi < 3; mi++)                                            \
        acc[mi][ni] = __builtin_amdgcn_mfma_f32_16x16x32_bf16(aF[mi], bF,       \
                                                              acc[mi][ni], 0, 0, 0); \
    }                                                                           \
  }

template <int MODE>
__global__ __launch_bounds__(256) void gemm_mfma(
    const u16* __restrict__ A, const u16* __restrict__ B, u16* __restrict__ C,
    float* __restrict__ statS, float* __restrict__ statQ, float* __restrict__ patchf,
    int K) {
  __shared__ u16 As[2][96][40];    // pitch 80 B
  __shared__ u16 Bs[2][32][64];    // pitch 128 B, XOR-16 column swizzle
  // T1: bijective XCD swizzle (gridDim.x % 8 == 0)
  int nwg = gridDim.x;
  int cpx = nwg >> 3;
  int j = (blockIdx.x & 7) * cpx + (blockIdx.x >> 3);
  int jm = j & 1;                           // M half (0: rows 0-95, 1: 96-191)
  int jc = j >> 1;                          // column tile 0..1567
  int n0 = jc * 64;
  int m0 = jm * 96;
  int tid = threadIdx.x;
  int wave = tid >> 6, lane = tid & 63;
  int wm = wave >> 1, wn = wave & 1;        // wave tile 48m x 32n
  int lg = lane >> 4, li = lane & 15;
  floatx4 acc[3][2] = {};

  int ar = tid >> 2, ak = (tid & 3) * 8;
  int bk = tid >> 3, bn = (tid & 7) * 8;
  int bnx = bn ^ ((bk >> 3) << 4);
  const u16* Ag = A + (size_t)(m0 + ar) * DIMC + ak;
  const u16* Bg = B + (size_t)bk * NG + n0 + bn;

  int nt = K / 32;                          // odd: 1, 7, 13, 19
  bool half = (ar < 32);

  // ---- single-tile prologue (tile 0) ----
  {
    uint4 p0 = *(const uint4*)(Ag);
    uint4 p1 = half ? *(const uint4*)(Ag + (size_t)64 * DIMC) : p0;
    uint4 pb = *(const uint4*)(Bg);
    *(uint4*)&As[0][ar][ak] = p0;
    if (half) *(uint4*)&As[0][ar + 64][ak] = p1;
    *(uint4*)&Bs[0][bk][bnx] = pb;
  }
  __syncthreads();
  uint4 a0A, a1A, bA, a0B, a1B, bB;         // staged pair (tiles p, p+1)
  if (nt > 1) {
    const u16* ag = Ag + 32;
    a0A = *(const uint4*)(ag);
    if (half) a1A = *(const uint4*)(ag + (size_t)64 * DIMC);
    bA = *(const uint4*)(Bg + (size_t)32 * NG);
    ag = Ag + 64;
    a0B = *(const uint4*)(ag);
    if (half) a1B = *(const uint4*)(ag + (size_t)64 * DIMC);
    bB = *(const uint4*)(Bg + (size_t)64 * NG);
  }
  GEMM_COMPUTE(0);
  __syncthreads();

  // ---- pair loop: tiles (p, p+1), p = 1,3,5,... ----
  for (int p = 1; p + 1 < nt; p += 2) {
    *(uint4*)&As[0][ar][ak] = a0A;
    if (half) *(uint4*)&As[0][ar + 64][ak] = a1A;
    *(uint4*)&Bs[0][bk][bnx] = bA;
    *(uint4*)&As[1][ar][ak] = a0B;
    if (half) *(uint4*)&As[1][ar + 64][ak] = a1B;
    *(uint4*)&Bs[1][bk][bnx] = bB;
    __syncthreads();
    if (p + 3 < nt) {                       // prefetch next pair (p+2, p+3)
      const u16* ag = Ag + (size_t)(p + 2) * 32;
      a0A = *(const uint4*)(ag);
      if (half) a1A = *(const uint4*)(ag + (size_t)64 * DIMC);
      bA = *(const uint4*)(Bg + (size_t)(p + 2) * 32 * NG);
      ag = Ag + (size_t)(p + 3) * 32;
      a0B = *(const uint4*)(ag);
      if (half) a1B = *(const uint4*)(ag + (size_t)64 * DIMC);
      bB = *(const uint4*)(Bg + (size_t)(p + 3) * 32 * NG);
    }
    GEMM_COMPUTE(0);
    GEMM_COMPUTE(1);
    __syncthreads();
  }

  if constexpr (MODE == 0) {
#pragma unroll
    for (int mi = 0; mi < 3; mi++) {
#pragma unroll
      for (int ni = 0; ni < 2; ni++) {
        int row = m0 + wm * 48 + mi * 16 + lg * 4;  // C/D: col=lane&15, row=lg*4+r
        int col = n0 + wn * 32 + ni * 16 + li;
        u16* cp = C + (size_t)row * NG + col;
#pragma unroll
        for (int r = 0; r < 4; r++) cp[(size_t)r * NG] = f2b(acc[mi][ni][r]);
      }
    }
  } else {
    int bg = jc / NTILE;
    int tile = jc % NTILE;
#pragma unroll
    for (int mi = 0; mi < 3; mi++) {
#pragma unroll
      for (int r = 0; r < 4; r++) {
        float v0 = acc[mi][0][r], v1 = acc[mi][1][r];
        float s = v0 + v1;
        float q = v0 * v0 + v1 * v1;
#pragma unroll
        for (int msk = 1; msk < 16; msk <<= 1) {
          s += __shfl_xor(s, msk);
          q += __shfl_xor(q, msk);
        }
        if (li == 0) {
          int row = m0 + wm * 48 + mi * 16 + lg * 4 + r;
          atomicAdd(&statS[row * 32 + bg], s);
          atomicAdd(&statQ[row * 32 + bg], q);
        }
      }
    }
    if (tile >= 22 && tile <= 24) {
#pragma unroll
      for (int mi = 0; mi < 3; mi++) {
#pragma unroll
        for (int ni = 0; ni < 2; ni++) {
          int row = m0 + wm * 48 + mi * 16 + lg * 4;
          int pc = (tile - 22) * 64 + wn * 32 + ni * 16 + li;
#pragma unroll
          for (int r = 0; r < 4; r++)
            patchf[((size_t)(row + r) * 32 + bg) * 192 + pc] = acc[mi][ni][r];
        }
      }
    }
  }
}

// ------- head: layer-4 norm + dwconv on patch, stats from GEMM epilogue -------
__global__ __launch_bounds__(256) void head_m4(
    const float* __restrict__ statS, const float* __restrict__ statQ,
    const float* __restrict__ patchf,
    const float* __restrict__ in_g, const float* __restrict__ in_b,
    const float* __restrict__ cdw, float* __restrict__ m4, float* __restrict__ meanH) {
  int idx = blockIdx.x * 256 + threadIdx.x;   // cl*32 + bg
  if (idx >= 192 * 32) return;
  int cl = idx >> 5;
  int c = 608 + cl;
  float mean = statS[idx] * (1.f / N_HW);
  float var = fmaxf(statQ[idx] * (1.f / N_HW) - mean * mean, 0.f);
  float sc = in_g[c] * rsqrtf(var + EPS);
  float sh = in_b[c] - mean * sc;
  const float* pf = patchf + (size_t)idx * 192;
  float val[4][4];
#pragma unroll
  for (int dy = 0; dy < 4; dy++)
#pragma unroll
    for (int dx = 0; dx < 4; dx++) {
      int hw = (25 + dy) * 56 + 25 + dx;
      float v = pf[((hw >> 6) - 22) * 64 + (hw & 63)];
      val[dy][dx] = fmaxf(v * sc + sh, 0.f);
    }
  const float* w = cdw + c * 9;
  float acc = 0.f;
#pragma unroll
  for (int oy = 1; oy < 3; oy++)
#pragma unroll
    for (int ox = 1; ox < 3; ox++)
#pragma unroll
      for (int ky = 0; ky < 3; ky++)
#pragma unroll
        for (int kx = 0; kx < 3; kx++)
          acc += val[oy + ky - 1][ox + kx - 1] * w[ky * 3 + kx];
  m4[idx] = acc * 0.25f;
  float mh = 0.f;
#pragma unroll
  for (int dy = 0; dy < 2; dy++)
#pragma unroll
    for (int dx = 0; dx < 2; dx++) {
      int hw = (26 + dy) * 56 + 26 + dx;
      mh += pf[((hw >> 6) - 22) * 64 + (hw & 63)];
    }
  meanH[idx] = mh * 0.25f;
}

__global__ __launch_bounds__(256) void head_mix(
    const float* __restrict__ gw, const float* __restrict__ m4, const float* __restrict__ meanH,
    float* __restrict__ out_pre) {
  int idx = blockIdx.x * 256 + threadIdx.x;   // bg*192 + j
  if (idx >= G * 192) return;
  int j = idx % 192;
  int bg = idx / 192;
  float acc = meanH[j * G + bg];
  const float* grow = gw + (size_t)(608 + j) * DIMC + 608;
  for (int c = 0; c < 192; c++) acc += grow[c] * m4[c * G + bg];
  out_pre[idx] = acc;
}

__global__ __launch_bounds__(256) void head_fc(
    const float* __restrict__ out_pre, const float* __restrict__ fc_w,
    const float* __restrict__ fc_b, float* __restrict__ outg) {
  int idx = blockIdx.x * 256 + threadIdx.x;   // bg*1000 + t
  if (idx >= G * 1000) return;
  int t = idx % 1000;
  int bg = idx / 1000;
  float acc = fc_b[t];
  const float* wr = fc_w + (size_t)t * 192;
  const float* hr = out_pre + (size_t)bg * 192;
  for (int j = 0; j < 192; j++) acc += wr[j] * hr[j];
  outg[idx] = acc;
}

extern "C" void kernel_launch(void* const* d_in, const int* in_sizes, int n_in,
                              void* d_out, int out_size, void* d_ws, size_t ws_size,
                              hipStream_t stream) {
  const float* x      = (const float*)d_in[0];
  const float* ds_w1  = (const float*)d_in[1];
  const float* ds_b1  = (const float*)d_in[2];
  const float* bn1_g  = (const float*)d_in[3];
  const float* bn1_b  = (const float*)d_in[4];
  const float* bn1_m  = (const float*)d_in[5];
  const float* bn1_v  = (const float*)d_in[6];
  const float* ds_dw  = (const float*)d_in[7];
  const float* ds_dwb = (const float*)d_in[8];
  const float* ds_w2  = (const float*)d_in[9];
  const float* ds_b2  = (const float*)d_in[10];
  const float* bn2_g  = (const float*)d_in[11];
  const float* bn2_b  = (const float*)d_in[12];
  const float* bn2_m  = (const float*)d_in[13];
  const float* bn2_v  = (const float*)d_in[14];
  const float* cdw    = (const float*)d_in[15];
  const float* gw     = (const float*)d_in[16];
  const float* in_g   = (const float*)d_in[17];
  const float* in_b   = (const float*)d_in[18];
  const float* fc_w   = (const float*)d_in[19];
  const float* fc_b   = (const float*)d_in[20];
  float* out = (float*)d_out;
  char* ws = (char*)d_ws;

  if (ws_size < NEED) return;

  u16*   XAc    = (u16*)(ws + XA_OFF);
  float* H0     = (float*)(ws + H0_OFF);
  u16*   blockb = (u16*)(ws + BLK_OFF);
  u16*   gwb    = (u16*)(ws + GWB_OFF);
  float* statS  = (float*)(ws + STS_OFF);
  float* statQ  = (float*)(ws + STQ_OFF);
  float* patchf = (float*)(ws + PAT_OFF);
  float* m4     = (float*)(ws + M4_OFF);
  float* meanH  = (float*)(ws + MH_OFF);
  float* opre   = (float*)(ws + OP_OFF);
  float* h1     = (float*)(ws + BLK_OFF);           // stem temps alias blockb
  float* h2     = h1 + (size_t)16 * G * 12544;

  gw2bf<<<625, 256, 0, stream>>>(gw, gwb);
  zero_stats<<<48, 256, 0, stream>>>(statS);        // statS+statQ contiguous

  static const int CDWOFF[4] = {0, 32, 224, 416};   // dw layer channel base
  static const int SZ[4]     = {32, 192, 192, 192};
  static const int RA[4]     = {32, 224, 416, 608}; // gemm output channel base
  static const int KK[4]     = {32, 224, 416, 608};

  stem_conv1<<<14 * G, 256, 0, stream>>>(
      x, ds_w1, ds_b1, bn1_g, bn1_b, bn1_m, bn1_v, h1);
  stem_dw<<<16 * G * N_HW / 256, 256, 0, stream>>>(h1, ds_dw, ds_dwb, h2);
  stem_pw<<<32 * G * N_HW / 256, 256, 0, stream>>>(
      h2, ds_w2, ds_b2, bn2_g, bn2_b, bn2_m, bn2_v, H0);

  for (int i = 0; i < 4; i++) {
    if (i == 0)
      dw_fused<float><<<SZ[i] * G, 256, 0, stream>>>(
          H0, cdw, in_g, in_b, XAc + (size_t)CDWOFF[i] * NG, CDWOFF[i]);
    else
      dw_fused<u16><<<SZ[i] * G, 256, 0, stream>>>(
          blockb, cdw, in_g, in_b, XAc + (size_t)CDWOFF[i] * NG, CDWOFF[i]);
    if (i < 3)
      gemm_mfma<0><<<NG / 32, 256, 0, stream>>>(
          gwb + (size_t)RA[i] * DIMC, XAc, blockb, nullptr, nullptr, nullptr, KK[i]);
    else
      gemm_mfma<1><<<NG / 32, 256, 0, stream>>>(
          gwb + (size_t)RA[i] * DIMC, XAc, nullptr, statS, statQ, patchf, KK[i]);
  }

  head_m4<<<24, 256, 0, stream>>>(statS, statQ, patchf, in_g, in_b, cdw, m4, meanH);
  head_mix<<<(G * 192 + 255) / 256, 256, 0, stream>>>(gw, m4, meanH, opre);
  head_fc<<<(G * 1000 + 255) / 256, 256, 0, stream>>>(opre, fc_w, fc_b, out);
}